// Round 2
// baseline (1223.157 us; speedup 1.0000x reference)
//
#include <hip/hip_runtime.h>
#include <math.h>

#define NPTS 65536
#define KNB  16

__device__ __forceinline__ float gelu_f(float v) {
    return 0.5f * v * (1.0f + erff(v * 0.70710678118654752f));
}

// ---------------------------------------------------------------------------
// Neighbor embedding: per point p, per neighbor k:
//   in7 = [xyz[j]-xyz[p], x[j]]  (j = knn[p][k])
//   h16 = gelu(in7@W1 * g1 + b1); h32 = gelu(h16@W2 * g2 + b2); h96 = h32@W3
//   f[p] = (max_k h96) * ng + nb
// 16 threads per point (one per neighbor). Stage 3 computed per-lane for all
// 96 dims (chunks of 16), then butterfly max across the 16-lane k-group.
// ---------------------------------------------------------------------------
__global__ __launch_bounds__(256) void ne_kernel(
    const float* __restrict__ x, const float* __restrict__ xyz,
    const int* __restrict__ knn,
    const float* __restrict__ w1, const float* __restrict__ g1, const float* __restrict__ b1,
    const float* __restrict__ w2, const float* __restrict__ g2, const float* __restrict__ b2,
    const float* __restrict__ w3,   // [32][96], read with wave-uniform indices
    const float* __restrict__ ng, const float* __restrict__ nb,
    float* __restrict__ f)
{
    __shared__ float w1s[7 * 16];
    __shared__ float w2s[16 * 32];
    __shared__ float g1s[16], b1s[16], g2s[32], b2s[32];

    const int tid = threadIdx.x;
    for (int i = tid; i < 112; i += 256) w1s[i] = w1[i];
    for (int i = tid; i < 512; i += 256) w2s[i] = w2[i];
    if (tid < 16) { g1s[tid] = g1[tid]; b1s[tid] = b1[tid]; }
    if (tid < 32) { g2s[tid] = g2[tid]; b2s[tid] = b2[tid]; }
    __syncthreads();

    const int pl = tid >> 4;          // local point 0..15
    const int k  = tid & 15;          // neighbor index
    const int p  = blockIdx.x * 16 + pl;
    const int j  = knn[p * KNB + k];

    float in7[7];
    {
        float cx0 = xyz[p * 3 + 0], cx1 = xyz[p * 3 + 1], cx2 = xyz[p * 3 + 2];
        in7[0] = xyz[j * 3 + 0] - cx0;
        in7[1] = xyz[j * 3 + 1] - cx1;
        in7[2] = xyz[j * 3 + 2] - cx2;
        in7[3] = x[j * 4 + 0];
        in7[4] = x[j * 4 + 1];
        in7[5] = x[j * 4 + 2];
        in7[6] = x[j * 4 + 3];
    }

    float h16[16];
#pragma unroll
    for (int o = 0; o < 16; ++o) {
        float s = 0.f;
#pragma unroll
        for (int c = 0; c < 7; ++c) s += in7[c] * w1s[c * 16 + o];
        h16[o] = gelu_f(s * g1s[o] + b1s[o]);
    }

    float h32[32];
#pragma unroll
    for (int o = 0; o < 32; ++o) {
        float s = 0.f;
#pragma unroll
        for (int c = 0; c < 16; ++c) s += h16[c] * w2s[c * 32 + o];
        h32[o] = gelu_f(s * g2s[o] + b2s[o]);
    }

    float* frow = f + (size_t)p * 96;
#pragma unroll 1
    for (int cc = 0; cc < 6; ++cc) {
        float acc[16];
#pragma unroll
        for (int jj = 0; jj < 16; ++jj) acc[jj] = 0.f;
#pragma unroll
        for (int c = 0; c < 32; ++c) {
            const float a = h32[c];
            const float* wrow = w3 + c * 96 + cc * 16;   // wave-uniform address
#pragma unroll
            for (int jj = 0; jj < 16; ++jj) acc[jj] += a * wrow[jj];
        }
        // max over the 16 neighbors (lanes k = lane%16)
#pragma unroll
        for (int jj = 0; jj < 16; ++jj) {
            float v = acc[jj];
            v = fmaxf(v, __shfl_xor(v, 1));
            v = fmaxf(v, __shfl_xor(v, 2));
            v = fmaxf(v, __shfl_xor(v, 4));
            v = fmaxf(v, __shfl_xor(v, 8));
            acc[jj] = v;
        }
        if (k == 0) {
#pragma unroll
            for (int jj = 0; jj < 16; ++jj) {
                const int d = cc * 16 + jj;
                frow[d] = acc[jj] * ng[d] + nb[d];
            }
        }
    }
}

// ---------------------------------------------------------------------------
// Generic fp32 GEMM: out-op(A[M,Kd] @ W[Kd,Nd]).
// MODE 0: out = gelu(acc + bias[c])                       (mlp first layer)
// MODE 1: out[r,c] += acc*g[c] + b[c]                     (mlp second layer + BN + residual)
// MODE 2: out = acc                                       (LFP projection)
// MODE 3: A loaded as A*g[k]+b[k] (prologue BN), out=acc  (head)
// Tile 64x64, 256 threads, 4x4 per thread, BK=32.
// ---------------------------------------------------------------------------
template <int MODE>
__global__ __launch_bounds__(256) void gemm_kernel(
    const float* __restrict__ A, const float* __restrict__ W,
    const float* __restrict__ bias,
    const float* __restrict__ g, const float* __restrict__ b,
    float* __restrict__ out, int Kd, int Nd)
{
    __shared__ float As[64][33];
    __shared__ float Bs[32][68];

    const int tid  = threadIdx.x;
    const int row0 = blockIdx.y * 64;
    const int c0   = blockIdx.x * 64;
    const int tr   = tid >> 4;     // 0..15
    const int tc   = tid & 15;     // 0..15

    float acc[4][4];
#pragma unroll
    for (int i = 0; i < 4; ++i)
#pragma unroll
        for (int jj = 0; jj < 4; ++jj) acc[i][jj] = 0.f;

    for (int k0 = 0; k0 < Kd; k0 += 32) {
        // A tile 64x32
        {
            const int r  = tid >> 3;          // 0..31
            const int c4 = (tid & 7) * 4;     // 0..28
#pragma unroll
            for (int pp = 0; pp < 2; ++pp) {
                const int rr = r + pp * 32;
                float4 v = *(const float4*)(A + (size_t)(row0 + rr) * Kd + k0 + c4);
                if (MODE == 3) {
                    v.x = v.x * g[k0 + c4 + 0] + b[k0 + c4 + 0];
                    v.y = v.y * g[k0 + c4 + 1] + b[k0 + c4 + 1];
                    v.z = v.z * g[k0 + c4 + 2] + b[k0 + c4 + 2];
                    v.w = v.w * g[k0 + c4 + 3] + b[k0 + c4 + 3];
                }
                As[rr][c4 + 0] = v.x; As[rr][c4 + 1] = v.y;
                As[rr][c4 + 2] = v.z; As[rr][c4 + 3] = v.w;
            }
        }
        // B tile 32x64
        {
            const int kr  = tid >> 4;         // 0..15
            const int cc4 = (tid & 15) * 4;   // 0..60
#pragma unroll
            for (int pp = 0; pp < 2; ++pp) {
                const int kk = kr + pp * 16;
                float4 v = make_float4(0.f, 0.f, 0.f, 0.f);
                if (c0 + cc4 < Nd)
                    v = *(const float4*)(W + (size_t)(k0 + kk) * Nd + c0 + cc4);
                *(float4*)&Bs[kk][cc4] = v;
            }
        }
        __syncthreads();
#pragma unroll
        for (int kk = 0; kk < 32; ++kk) {
            const float a0 = As[tr * 4 + 0][kk];
            const float a1 = As[tr * 4 + 1][kk];
            const float a2 = As[tr * 4 + 2][kk];
            const float a3 = As[tr * 4 + 3][kk];
            const float4 bv = *(const float4*)&Bs[kk][tc * 4];
            acc[0][0] += a0 * bv.x; acc[0][1] += a0 * bv.y; acc[0][2] += a0 * bv.z; acc[0][3] += a0 * bv.w;
            acc[1][0] += a1 * bv.x; acc[1][1] += a1 * bv.y; acc[1][2] += a1 * bv.z; acc[1][3] += a1 * bv.w;
            acc[2][0] += a2 * bv.x; acc[2][1] += a2 * bv.y; acc[2][2] += a2 * bv.z; acc[2][3] += a2 * bv.w;
            acc[3][0] += a3 * bv.x; acc[3][1] += a3 * bv.y; acc[3][2] += a3 * bv.z; acc[3][3] += a3 * bv.w;
        }
        __syncthreads();
    }

#pragma unroll
    for (int i = 0; i < 4; ++i) {
        const int row = row0 + tr * 4 + i;
#pragma unroll
        for (int jj = 0; jj < 4; ++jj) {
            const int col = c0 + tc * 4 + jj;
            if (col >= Nd) continue;
            const float v = acc[i][jj];
            if (MODE == 0) {
                out[(size_t)row * Nd + col] = gelu_f(v + bias[col]);
            } else if (MODE == 1) {
                out[(size_t)row * Nd + col] += v * g[col] + b[col];
            } else {
                out[(size_t)row * Nd + col] = v;
            }
        }
    }
}

// ---------------------------------------------------------------------------
// LFP gather-max:  f[p] += ( max_k y[knn[p][k]] - y[p] ) * g + b
// 16 threads per point, 6 dims per thread.
// ---------------------------------------------------------------------------
__global__ __launch_bounds__(256) void gathermax_kernel(
    const float* __restrict__ y, const int* __restrict__ knn,
    const float* __restrict__ g, const float* __restrict__ b,
    float* __restrict__ f)
{
    __shared__ int knns[16][16];
    const int tid = threadIdx.x;
    const int pl  = tid >> 4;
    const int t   = tid & 15;
    const int p0  = blockIdx.x * 16;
    knns[pl][t] = knn[(p0 + pl) * KNB + t];
    __syncthreads();

    const int p   = p0 + pl;
    const int off = t * 6;

    float m[6];
#pragma unroll
    for (int i = 0; i < 6; ++i) m[i] = -INFINITY;

#pragma unroll 1
    for (int k = 0; k < 16; ++k) {
        const int j = knns[pl][k];
        const float* yr = y + (size_t)j * 96 + off;
        const float2 v0 = *(const float2*)(yr + 0);
        const float2 v1 = *(const float2*)(yr + 2);
        const float2 v2 = *(const float2*)(yr + 4);
        m[0] = fmaxf(m[0], v0.x); m[1] = fmaxf(m[1], v0.y);
        m[2] = fmaxf(m[2], v1.x); m[3] = fmaxf(m[3], v1.y);
        m[4] = fmaxf(m[4], v2.x); m[5] = fmaxf(m[5], v2.y);
    }

    const float* yc = y + (size_t)p * 96 + off;
    float* fr = f + (size_t)p * 96 + off;
#pragma unroll
    for (int i = 0; i < 6; ++i) {
        fr[i] += (m[i] - yc[i]) * g[off + i] + b[off + i];
    }
}

// ---------------------------------------------------------------------------
extern "C" void kernel_launch(void* const* d_in, const int* in_sizes, int n_in,
                              void* d_out, int out_size, void* d_ws, size_t ws_size,
                              hipStream_t stream)
{
    const float* x     = (const float*)d_in[0];
    const float* xyz   = (const float*)d_in[1];
    const int*   knn   = (const int*)d_in[2];
    const float* ne_w1 = (const float*)d_in[3];
    const float* ne_g1 = (const float*)d_in[4];
    const float* ne_b1 = (const float*)d_in[5];
    const float* ne_w2 = (const float*)d_in[6];
    const float* ne_g2 = (const float*)d_in[7];
    const float* ne_b2 = (const float*)d_in[8];
    const float* ne_w3 = (const float*)d_in[9];
    const float* nbr_g = (const float*)d_in[10];
    const float* nbr_b = (const float*)d_in[11];
    const float* m0_w1 = (const float*)d_in[12];
    const float* m0_b1 = (const float*)d_in[13];
    const float* m0_w2 = (const float*)d_in[14];
    const float* m0_g  = (const float*)d_in[15];
    const float* m0_b  = (const float*)d_in[16];
    const float* lfp_w = (const float*)d_in[17];
    const float* lfp_g = (const float*)d_in[18];
    const float* lfp_b = (const float*)d_in[19];
    const float* ms_w1 = (const float*)d_in[20];
    const float* ms_b1 = (const float*)d_in[21];
    const float* ms_w2 = (const float*)d_in[22];
    const float* ms_g  = (const float*)d_in[23];
    const float* ms_b  = (const float*)d_in[24];
    const float* pp_g  = (const float*)d_in[25];
    const float* pp_b  = (const float*)d_in[26];
    const float* pp_w  = (const float*)d_in[27];

    float* out = (float*)d_out;

    // Workspace layout: f [N,96]; h [N,384]; y aliases h (disjoint lifetimes).
    float* f = (float*)d_ws;                      // [N,96]
    float* h = f + (size_t)NPTS * 96;             // [N,384]
    float* y = h;                                 // [N,96] alias

    // --- neighbor embedding ---
    ne_kernel<<<NPTS / 16, 256, 0, stream>>>(x, xyz, knn,
        ne_w1, ne_g1, ne_b1, ne_w2, ne_g2, ne_b2, ne_w3, nbr_g, nbr_b, f);

    // --- mlp helper: f += bn(gelu(f@w1+b1)@w2) ---
    auto mlp = [&](const float* w1, const float* b1, const float* w2,
                   const float* gg, const float* bb) {
        gemm_kernel<0><<<dim3(6, NPTS / 64), 256, 0, stream>>>(
            f, w1, b1, nullptr, nullptr, h, 96, 384);
        gemm_kernel<1><<<dim3(2, NPTS / 64), 256, 0, stream>>>(
            h, w2, nullptr, gg, bb, f, 384, 96);
    };

    mlp(m0_w1, m0_b1, m0_w2, m0_g, m0_b);

    for (int i = 0; i < 4; ++i) {
        gemm_kernel<2><<<dim3(2, NPTS / 64), 256, 0, stream>>>(
            f, lfp_w + (size_t)i * 96 * 96, nullptr, nullptr, nullptr, y, 96, 96);
        gathermax_kernel<<<NPTS / 16, 256, 0, stream>>>(
            y, knn, lfp_g + i * 96, lfp_b + i * 96, f);
        if (i & 1) {
            const int jj = i / 2;
            mlp(ms_w1 + (size_t)jj * 96 * 384, ms_b1 + (size_t)jj * 384,
                ms_w2 + (size_t)jj * 384 * 96, ms_g + jj * 96, ms_b + jj * 96);
        }
    }

    // --- head: out = (f*pp_g+pp_b) @ pp_w ---
    gemm_kernel<3><<<dim3(4, NPTS / 64), 256, 0, stream>>>(
        f, pp_w, nullptr, pp_g, pp_b, out, 96, 256);
}

// Round 3
// 783.882 us; speedup vs baseline: 1.5604x; 1.5604x over previous
//
#include <hip/hip_runtime.h>
#include <hip/hip_bf16.h>
#include <math.h>

#define NPTS 65536
#define KNB  16

typedef __attribute__((ext_vector_type(8))) short bf16x8;
typedef __attribute__((ext_vector_type(4))) float f32x4;

__device__ __forceinline__ float gelu_f(float v) {
    return 0.5f * v * (1.0f + erff(v * 0.70710678118654752f));
}

// ---------------------------------------------------------------------------
// Weight prep (runs every launch; graph-safe): transpose all GEMM weights to
// W^T [N][K] bf16 so both GEMM operands stream as [row][k]. For the head,
// fold BN into weights: bn(f)@W = f@(g*W) + (b@W); b@W is a 256-vector c_pp.
// ---------------------------------------------------------------------------
__global__ __launch_bounds__(256) void prep_weights(
    const float* __restrict__ m0_w1, const float* __restrict__ m0_w2,
    const float* __restrict__ ms_w1, const float* __restrict__ ms_w2,
    const float* __restrict__ lfp_w,
    const float* __restrict__ pp_w, const float* __restrict__ pp_g,
    const float* __restrict__ pp_b,
    __hip_bfloat16* __restrict__ w_m0w1t, __hip_bfloat16* __restrict__ w_m0w2t,
    __hip_bfloat16* __restrict__ w_msw1t, __hip_bfloat16* __restrict__ w_msw2t,
    __hip_bfloat16* __restrict__ w_lfpt,  __hip_bfloat16* __restrict__ w_ppt,
    float* __restrict__ c_pp)
{
    int idx = blockIdx.x * 256 + threadIdx.x;
    if (idx < 36864) {                       // m0_w1^T [384][96]
        int n = idx / 96, k = idx % 96;
        w_m0w1t[idx] = __float2bfloat16(m0_w1[k * 384 + n]);
        return;
    }
    idx -= 36864;
    if (idx < 36864) {                       // m0_w2^T [96][384]
        int n = idx / 384, k = idx % 384;
        w_m0w2t[idx] = __float2bfloat16(m0_w2[k * 96 + n]);
        return;
    }
    idx -= 36864;
    if (idx < 2 * 36864) {                   // ms_w1^T[j] [384][96]
        int j = idx / 36864, r = idx % 36864;
        int n = r / 96, k = r % 96;
        w_msw1t[idx] = __float2bfloat16(ms_w1[j * 36864 + k * 384 + n]);
        return;
    }
    idx -= 2 * 36864;
    if (idx < 2 * 36864) {                   // ms_w2^T[j] [96][384]
        int j = idx / 36864, r = idx % 36864;
        int n = r / 384, k = r % 384;
        w_msw2t[idx] = __float2bfloat16(ms_w2[j * 36864 + k * 96 + n]);
        return;
    }
    idx -= 2 * 36864;
    if (idx < 4 * 9216) {                    // lfp_w^T[i] [96][96]
        int i = idx / 9216, r = idx % 9216;
        int n = r / 96, k = r % 96;
        w_lfpt[idx] = __float2bfloat16(lfp_w[i * 9216 + k * 96 + n]);
        return;
    }
    idx -= 4 * 9216;
    if (idx < 24576) {                       // (pp_g * pp_w)^T [256][96]
        int n = idx / 96, k = idx % 96;
        w_ppt[idx] = __float2bfloat16(pp_g[k] * pp_w[k * 256 + n]);
        return;
    }
    idx -= 24576;
    if (idx < 256) {                         // c_pp[n] = sum_k pp_b[k]*pp_w[k][n]
        float s = 0.f;
        for (int k = 0; k < 96; ++k) s += pp_b[k] * pp_w[k * 256 + idx];
        c_pp[idx] = s;
    }
}

// ---------------------------------------------------------------------------
// Neighbor embedding (fp32, unchanged logic; now also emits bf16 copy of f).
// ---------------------------------------------------------------------------
__global__ __launch_bounds__(256) void ne_kernel(
    const float* __restrict__ x, const float* __restrict__ xyz,
    const int* __restrict__ knn,
    const float* __restrict__ w1, const float* __restrict__ g1, const float* __restrict__ b1,
    const float* __restrict__ w2, const float* __restrict__ g2, const float* __restrict__ b2,
    const float* __restrict__ w3,
    const float* __restrict__ ng, const float* __restrict__ nb,
    float* __restrict__ f, __hip_bfloat16* __restrict__ fbf)
{
    __shared__ float w1s[7 * 16];
    __shared__ float w2s[16 * 32];
    __shared__ float g1s[16], b1s[16], g2s[32], b2s[32];

    const int tid = threadIdx.x;
    for (int i = tid; i < 112; i += 256) w1s[i] = w1[i];
    for (int i = tid; i < 512; i += 256) w2s[i] = w2[i];
    if (tid < 16) { g1s[tid] = g1[tid]; b1s[tid] = b1[tid]; }
    if (tid < 32) { g2s[tid] = g2[tid]; b2s[tid] = b2[tid]; }
    __syncthreads();

    const int pl = tid >> 4;
    const int k  = tid & 15;
    const int p  = blockIdx.x * 16 + pl;
    const int j  = knn[p * KNB + k];

    float in7[7];
    {
        float cx0 = xyz[p * 3 + 0], cx1 = xyz[p * 3 + 1], cx2 = xyz[p * 3 + 2];
        in7[0] = xyz[j * 3 + 0] - cx0;
        in7[1] = xyz[j * 3 + 1] - cx1;
        in7[2] = xyz[j * 3 + 2] - cx2;
        in7[3] = x[j * 4 + 0];
        in7[4] = x[j * 4 + 1];
        in7[5] = x[j * 4 + 2];
        in7[6] = x[j * 4 + 3];
    }

    float h16[16];
#pragma unroll
    for (int o = 0; o < 16; ++o) {
        float s = 0.f;
#pragma unroll
        for (int c = 0; c < 7; ++c) s += in7[c] * w1s[c * 16 + o];
        h16[o] = gelu_f(s * g1s[o] + b1s[o]);
    }

    float h32[32];
#pragma unroll
    for (int o = 0; o < 32; ++o) {
        float s = 0.f;
#pragma unroll
        for (int c = 0; c < 16; ++c) s += h16[c] * w2s[c * 32 + o];
        h32[o] = gelu_f(s * g2s[o] + b2s[o]);
    }

    float* frow = f + (size_t)p * 96;
    __hip_bfloat16* fbrow = fbf + (size_t)p * 96;
#pragma unroll 1
    for (int cc = 0; cc < 6; ++cc) {
        float acc[16];
#pragma unroll
        for (int jj = 0; jj < 16; ++jj) acc[jj] = 0.f;
#pragma unroll
        for (int c = 0; c < 32; ++c) {
            const float a = h32[c];
            const float* wrow = w3 + c * 96 + cc * 16;
#pragma unroll
            for (int jj = 0; jj < 16; ++jj) acc[jj] += a * wrow[jj];
        }
#pragma unroll
        for (int jj = 0; jj < 16; ++jj) {
            float v = acc[jj];
            v = fmaxf(v, __shfl_xor(v, 1));
            v = fmaxf(v, __shfl_xor(v, 2));
            v = fmaxf(v, __shfl_xor(v, 4));
            v = fmaxf(v, __shfl_xor(v, 8));
            acc[jj] = v;
        }
        if (k == 0) {
#pragma unroll
            for (int jj = 0; jj < 16; ++jj) {
                const int d = cc * 16 + jj;
                const float v = acc[jj] * ng[d] + nb[d];
                frow[d] = v;
                fbrow[d] = __float2bfloat16(v);
            }
        }
    }
}

// ---------------------------------------------------------------------------
// MFMA GEMM: D = A[M,K]bf16 @ Bt[N,K]bf16^T, tile 64 x (16*NT), 4 waves.
// Wave w owns rows 16w..16w+15; NT 16x16 col tiles; K-step 32.
// Fragment layout (16x16x32): row/col = lane%16, k = 8*(lane>>4)+e.
// (Any common k-permutation between A and B frags cancels in the dot.)
// MODE 0: bfout = bf16(gelu(acc + bias[col]))            (MLP layer 1 -> h)
// MODE 1: f += acc*g+b; fout=f, bfout=bf16(f)            (MLP layer 2)
// MODE 2: fout = acc                                     (LFP projection -> y)
// MODE 3: fout = acc + bias[col]                         (head, BN pre-folded)
// ---------------------------------------------------------------------------
template <int MODE, int NT>
__global__ __launch_bounds__(256) void mfma_gemm(
    const __hip_bfloat16* __restrict__ A,
    const __hip_bfloat16* __restrict__ Bt,
    const float* __restrict__ bias,
    const float* __restrict__ g, const float* __restrict__ bvec,
    float* __restrict__ fout,
    __hip_bfloat16* __restrict__ bfout,
    int K, int N)
{
    constexpr int BN = 16 * NT;
    __shared__ short As[64][40];   // pad 32->40 shorts: 80B rows, 2-way-free banks
    __shared__ short Bs[BN][40];

    const int tid  = threadIdx.x;
    const int wave = tid >> 6;
    const int lane = tid & 63;
    const int row0 = blockIdx.y * 64;
    const int c0   = blockIdx.x * BN;

    f32x4 acc[NT];
#pragma unroll
    for (int i = 0; i < NT; ++i) acc[i] = f32x4{0.f, 0.f, 0.f, 0.f};

    const int sr = tid >> 2;         // staging row 0..63
    const int sk = (tid & 3) * 8;    // staging k-chunk
    const short* Ag = (const short*)A;
    const short* Bg = (const short*)Bt;

    for (int k0 = 0; k0 < K; k0 += 32) {
        *(bf16x8*)&As[sr][sk] =
            *(const bf16x8*)&Ag[(size_t)(row0 + sr) * K + k0 + sk];
        for (int idx = tid; idx < BN * 4; idx += 256) {
            const int r = idx >> 2, ko = (idx & 3) * 8;
            *(bf16x8*)&Bs[r][ko] =
                *(const bf16x8*)&Bg[(size_t)(c0 + r) * K + k0 + ko];
        }
        __syncthreads();

        const int kc = (lane >> 4) * 8;
        const bf16x8 av = *(const bf16x8*)&As[wave * 16 + (lane & 15)][kc];
#pragma unroll
        for (int ct = 0; ct < NT; ++ct) {
            const bf16x8 bv = *(const bf16x8*)&Bs[ct * 16 + (lane & 15)][kc];
            acc[ct] = __builtin_amdgcn_mfma_f32_16x16x32_bf16(av, bv, acc[ct], 0, 0, 0);
        }
        __syncthreads();
    }

    const int erow = row0 + wave * 16 + ((lane >> 4) << 2);
    const int ecl  = lane & 15;
#pragma unroll
    for (int ct = 0; ct < NT; ++ct) {
        const int col = c0 + ct * 16 + ecl;
#pragma unroll
        for (int r = 0; r < 4; ++r) {
            const int row = erow + r;
            const float v = acc[ct][r];
            if (MODE == 0) {
                bfout[(size_t)row * N + col] = __float2bfloat16(gelu_f(v + bias[col]));
            } else if (MODE == 1) {
                const size_t o = (size_t)row * N + col;
                const float nf = fout[o] + v * g[col] + bvec[col];
                fout[o] = nf;
                bfout[o] = __float2bfloat16(nf);
            } else if (MODE == 2) {
                fout[(size_t)row * N + col] = v;
            } else {
                fout[(size_t)row * N + col] = v + bias[col];
            }
        }
    }
}

// ---------------------------------------------------------------------------
// LFP gather-max:  f[p] += ( max_k y[knn[p][k]] - y[p] ) * g + b; emits bf16 f.
// ---------------------------------------------------------------------------
__global__ __launch_bounds__(256) void gathermax_kernel(
    const float* __restrict__ y, const int* __restrict__ knn,
    const float* __restrict__ g, const float* __restrict__ b,
    float* __restrict__ f, __hip_bfloat16* __restrict__ fbf)
{
    __shared__ int knns[16][16];
    const int tid = threadIdx.x;
    const int pl  = tid >> 4;
    const int t   = tid & 15;
    const int p0  = blockIdx.x * 16;
    knns[pl][t] = knn[(p0 + pl) * KNB + t];
    __syncthreads();

    const int p   = p0 + pl;
    const int off = t * 6;

    float m[6];
#pragma unroll
    for (int i = 0; i < 6; ++i) m[i] = -INFINITY;

#pragma unroll 1
    for (int k = 0; k < 16; ++k) {
        const int j = knns[pl][k];
        const float* yr = y + (size_t)j * 96 + off;
        const float2 v0 = *(const float2*)(yr + 0);
        const float2 v1 = *(const float2*)(yr + 2);
        const float2 v2 = *(const float2*)(yr + 4);
        m[0] = fmaxf(m[0], v0.x); m[1] = fmaxf(m[1], v0.y);
        m[2] = fmaxf(m[2], v1.x); m[3] = fmaxf(m[3], v1.y);
        m[4] = fmaxf(m[4], v2.x); m[5] = fmaxf(m[5], v2.y);
    }

    const float* yc = y + (size_t)p * 96 + off;
    float* fr = f + (size_t)p * 96 + off;
    __hip_bfloat16* fbr = fbf + (size_t)p * 96 + off;
#pragma unroll
    for (int i = 0; i < 6; ++i) {
        const float nf = fr[i] + (m[i] - yc[i]) * g[off + i] + b[off + i];
        fr[i] = nf;
        fbr[i] = __float2bfloat16(nf);
    }
}

// ---------------------------------------------------------------------------
extern "C" void kernel_launch(void* const* d_in, const int* in_sizes, int n_in,
                              void* d_out, int out_size, void* d_ws, size_t ws_size,
                              hipStream_t stream)
{
    const float* x     = (const float*)d_in[0];
    const float* xyz   = (const float*)d_in[1];
    const int*   knn   = (const int*)d_in[2];
    const float* ne_w1 = (const float*)d_in[3];
    const float* ne_g1 = (const float*)d_in[4];
    const float* ne_b1 = (const float*)d_in[5];
    const float* ne_w2 = (const float*)d_in[6];
    const float* ne_g2 = (const float*)d_in[7];
    const float* ne_b2 = (const float*)d_in[8];
    const float* ne_w3 = (const float*)d_in[9];
    const float* nbr_g = (const float*)d_in[10];
    const float* nbr_b = (const float*)d_in[11];
    const float* m0_w1 = (const float*)d_in[12];
    const float* m0_b1 = (const float*)d_in[13];
    const float* m0_w2 = (const float*)d_in[14];
    const float* m0_g  = (const float*)d_in[15];
    const float* m0_b  = (const float*)d_in[16];
    const float* lfp_w = (const float*)d_in[17];
    const float* lfp_g = (const float*)d_in[18];
    const float* lfp_b = (const float*)d_in[19];
    const float* ms_w1 = (const float*)d_in[20];
    const float* ms_b1 = (const float*)d_in[21];
    const float* ms_w2 = (const float*)d_in[22];
    const float* ms_g  = (const float*)d_in[23];
    const float* ms_b  = (const float*)d_in[24];
    const float* pp_g  = (const float*)d_in[25];
    const float* pp_b  = (const float*)d_in[26];
    const float* pp_w  = (const float*)d_in[27];

    float* out = (float*)d_out;

    // --- workspace layout (all 16B-aligned) ---
    float* f   = (float*)d_ws;                            // [N][96] f32
    float* y   = f + (size_t)NPTS * 96;                   // [N][96] f32
    __hip_bfloat16* fbf = (__hip_bfloat16*)(y + (size_t)NPTS * 96);  // [N][96] bf16
    __hip_bfloat16* h   = fbf + (size_t)NPTS * 96;        // [N][384] bf16
    __hip_bfloat16* w_m0w1t = h + (size_t)NPTS * 384;     // [384][96]
    __hip_bfloat16* w_m0w2t = w_m0w1t + 36864;            // [96][384]
    __hip_bfloat16* w_msw1t = w_m0w2t + 36864;            // 2x[384][96]
    __hip_bfloat16* w_msw2t = w_msw1t + 2 * 36864;        // 2x[96][384]
    __hip_bfloat16* w_lfpt  = w_msw2t + 2 * 36864;        // 4x[96][96]
    __hip_bfloat16* w_ppt   = w_lfpt + 4 * 9216;          // [256][96]
    float* c_pp = (float*)(w_ppt + 24576);                // [256] f32

    prep_weights<<<1105, 256, 0, stream>>>(
        m0_w1, m0_w2, ms_w1, ms_w2, lfp_w, pp_w, pp_g, pp_b,
        w_m0w1t, w_m0w2t, w_msw1t, w_msw2t, w_lfpt, w_ppt, c_pp);

    ne_kernel<<<NPTS / 16, 256, 0, stream>>>(x, xyz, knn,
        ne_w1, ne_g1, ne_b1, ne_w2, ne_g2, ne_b2, ne_w3, nbr_g, nbr_b, f, fbf);

    auto mlp = [&](const __hip_bfloat16* w1t, const float* b1,
                   const __hip_bfloat16* w2t, const float* gg, const float* bb) {
        mfma_gemm<0, 4><<<dim3(6, NPTS / 64), 256, 0, stream>>>(
            fbf, w1t, b1, nullptr, nullptr, nullptr, h, 96, 384);
        mfma_gemm<1, 6><<<dim3(1, NPTS / 64), 256, 0, stream>>>(
            h, w2t, nullptr, gg, bb, f, fbf, 384, 96);
    };

    mlp(w_m0w1t, m0_b1, w_m0w2t, m0_g, m0_b);

    for (int i = 0; i < 4; ++i) {
        mfma_gemm<2, 6><<<dim3(1, NPTS / 64), 256, 0, stream>>>(
            fbf, w_lfpt + (size_t)i * 9216, nullptr, nullptr, nullptr, y, nullptr, 96, 96);
        gathermax_kernel<<<NPTS / 16, 256, 0, stream>>>(
            y, knn, lfp_g + i * 96, lfp_b + i * 96, f, fbf);
        if (i & 1) {
            const int jj = i / 2;
            mlp(w_msw1t + (size_t)jj * 36864, ms_b1 + (size_t)jj * 384,
                w_msw2t + (size_t)jj * 36864, ms_g + jj * 96, ms_b + jj * 96);
        }
    }

    mfma_gemm<3, 4><<<dim3(4, NPTS / 64), 256, 0, stream>>>(
        fbf, w_ppt, c_pp, nullptr, nullptr, out, nullptr, 96, 256);
}

// Round 4
// 689.116 us; speedup vs baseline: 1.7750x; 1.1375x over previous
//
#include <hip/hip_runtime.h>
#include <hip/hip_bf16.h>
#include <math.h>

#define NPTS 65536
#define KNB  16

typedef __attribute__((ext_vector_type(8))) short bf16x8;
typedef __attribute__((ext_vector_type(4))) float f32x4;

__device__ __forceinline__ float gelu_f(float v) {
    return 0.5f * v * (1.0f + erff(v * 0.70710678118654752f));
}

__device__ __forceinline__ short f2bf_s(float v) {
    __hip_bfloat16 h = __float2bfloat16(v);
    return *reinterpret_cast<short*>(&h);
}

// ---------------------------------------------------------------------------
// Weight prep: transpose all GEMM weights to W^T [N][K] bf16. Head BN folded:
// bn(f)@W = f@(g*W) + (b@W); b@W precomputed into c_pp.
// ---------------------------------------------------------------------------
__global__ __launch_bounds__(256) void prep_weights(
    const float* __restrict__ m0_w1, const float* __restrict__ m0_w2,
    const float* __restrict__ ms_w1, const float* __restrict__ ms_w2,
    const float* __restrict__ lfp_w,
    const float* __restrict__ pp_w, const float* __restrict__ pp_g,
    const float* __restrict__ pp_b,
    __hip_bfloat16* __restrict__ w_m0w1t, __hip_bfloat16* __restrict__ w_m0w2t,
    __hip_bfloat16* __restrict__ w_msw1t, __hip_bfloat16* __restrict__ w_msw2t,
    __hip_bfloat16* __restrict__ w_lfpt,  __hip_bfloat16* __restrict__ w_ppt,
    float* __restrict__ c_pp)
{
    int idx = blockIdx.x * 256 + threadIdx.x;
    if (idx < 36864) {                       // m0_w1^T [384][96]
        int n = idx / 96, k = idx % 96;
        w_m0w1t[idx] = __float2bfloat16(m0_w1[k * 384 + n]);
        return;
    }
    idx -= 36864;
    if (idx < 36864) {                       // m0_w2^T [96][384]
        int n = idx / 384, k = idx % 384;
        w_m0w2t[idx] = __float2bfloat16(m0_w2[k * 96 + n]);
        return;
    }
    idx -= 36864;
    if (idx < 2 * 36864) {                   // ms_w1^T[j] [384][96]
        int j = idx / 36864, r = idx % 36864;
        int n = r / 96, k = r % 96;
        w_msw1t[idx] = __float2bfloat16(ms_w1[j * 36864 + k * 384 + n]);
        return;
    }
    idx -= 2 * 36864;
    if (idx < 2 * 36864) {                   // ms_w2^T[j] [96][384]
        int j = idx / 36864, r = idx % 36864;
        int n = r / 384, k = r % 384;
        w_msw2t[idx] = __float2bfloat16(ms_w2[j * 36864 + k * 96 + n]);
        return;
    }
    idx -= 2 * 36864;
    if (idx < 4 * 9216) {                    // lfp_w^T[i] [96][96]
        int i = idx / 9216, r = idx % 9216;
        int n = r / 96, k = r % 96;
        w_lfpt[idx] = __float2bfloat16(lfp_w[i * 9216 + k * 96 + n]);
        return;
    }
    idx -= 4 * 9216;
    if (idx < 24576) {                       // (pp_g * pp_w)^T [256][96]
        int n = idx / 96, k = idx % 96;
        w_ppt[idx] = __float2bfloat16(pp_g[k] * pp_w[k * 256 + n]);
        return;
    }
    idx -= 24576;
    if (idx < 256) {                         // c_pp[n] = sum_k pp_b[k]*pp_w[k][n]
        float s = 0.f;
        for (int k = 0; k < 96; ++k) s += pp_b[k] * pp_w[k * 256 + idx];
        c_pp[idx] = s;
    }
}

// ---------------------------------------------------------------------------
// Neighbor embedding, MFMA stage-3.
// Block = 256 threads = 16 points x 16 neighbors. Stages 1-2 per-edge fp32
// VALU -> h32 bf16 in LDS [256][40] (pad 40: 8-bank spread, 2-way free).
// Stage 3 + neighbor-max via MFMA: per point one A-tile (16 edges x 32),
// B = W3^T staged in LDS; 6 16x16x32 MFMAs; C-fragment rows = edges, so
// maxpool = 4-reg max + shfl_xor(16,32). Lanes 0-15 write BN'd f row.
// ---------------------------------------------------------------------------
__global__ __launch_bounds__(256) void ne_kernel(
    const float* __restrict__ x, const float* __restrict__ xyz,
    const int* __restrict__ knn,
    const float* __restrict__ w1, const float* __restrict__ g1, const float* __restrict__ b1,
    const float* __restrict__ w2, const float* __restrict__ g2, const float* __restrict__ b2,
    const float* __restrict__ w3,
    const float* __restrict__ ng, const float* __restrict__ nb,
    float* __restrict__ f, __hip_bfloat16* __restrict__ fbf)
{
    __shared__ float w1s[7 * 16];
    __shared__ float w2s[16 * 32];
    __shared__ float g1s[16], b1s[16], g2s[32], b2s[32];
    __shared__ float ngs[96], nbs[96];
    __shared__ short h32s[256][40];
    __shared__ short w3t[96][40];

    const int tid = threadIdx.x;
    for (int i = tid; i < 112; i += 256) w1s[i] = w1[i];
    for (int i = tid; i < 512; i += 256) w2s[i] = w2[i];
    if (tid < 16) { g1s[tid] = g1[tid]; b1s[tid] = b1[tid]; }
    if (tid < 32) { g2s[tid] = g2[tid]; b2s[tid] = b2[tid]; }
    if (tid < 96) { ngs[tid] = ng[tid]; nbs[tid] = nb[tid]; }
    for (int i = tid; i < 3072; i += 256) {
        const int c = i / 96, n = i % 96;            // coalesced read over n
        w3t[n][c] = f2bf_s(w3[i]);
    }
    __syncthreads();

    const int pl = tid >> 4;          // local point 0..15
    const int k  = tid & 15;          // neighbor
    const int p  = blockIdx.x * 16 + pl;
    const int j  = knn[p * KNB + k];

    float in7[7];
    {
        float cx0 = xyz[p * 3 + 0], cx1 = xyz[p * 3 + 1], cx2 = xyz[p * 3 + 2];
        in7[0] = xyz[j * 3 + 0] - cx0;
        in7[1] = xyz[j * 3 + 1] - cx1;
        in7[2] = xyz[j * 3 + 2] - cx2;
        in7[3] = x[j * 4 + 0];
        in7[4] = x[j * 4 + 1];
        in7[5] = x[j * 4 + 2];
        in7[6] = x[j * 4 + 3];
    }

    float h16[16];
#pragma unroll
    for (int o = 0; o < 16; ++o) {
        float s = 0.f;
#pragma unroll
        for (int c = 0; c < 7; ++c) s += in7[c] * w1s[c * 16 + o];
        h16[o] = gelu_f(s * g1s[o] + b1s[o]);
    }

    float h32[32];
#pragma unroll
    for (int o = 0; o < 32; ++o) {
        float s = 0.f;
#pragma unroll
        for (int c = 0; c < 16; ++c) s += h16[c] * w2s[c * 32 + o];
        h32[o] = gelu_f(s * g2s[o] + b2s[o]);
    }

    // h32 -> LDS (bf16), row = edge index within block
#pragma unroll
    for (int v8 = 0; v8 < 4; ++v8) {
        bf16x8 t;
#pragma unroll
        for (int e = 0; e < 8; ++e) t[e] = f2bf_s(h32[v8 * 8 + e]);
        *(bf16x8*)&h32s[tid][v8 * 8] = t;
    }
    __syncthreads();

    // --- MFMA stage 3 + maxpool: wave w handles points 4w..4w+3 ---
    const int wave = tid >> 6;
    const int lane = tid & 63;
    const int lr   = lane & 15;
    const int kc   = (lane >> 4) * 8;

    bf16x8 bv[6];
#pragma unroll
    for (int ct = 0; ct < 6; ++ct)
        bv[ct] = *(const bf16x8*)&w3t[ct * 16 + lr][kc];

    const f32x4 zero = {0.f, 0.f, 0.f, 0.f};
#pragma unroll
    for (int pp = 0; pp < 4; ++pp) {
        const int lpl = wave * 4 + pp;
        const int gp  = blockIdx.x * 16 + lpl;
        const bf16x8 av = *(const bf16x8*)&h32s[lpl * 16 + lr][kc];
#pragma unroll
        for (int ct = 0; ct < 6; ++ct) {
            f32x4 a = __builtin_amdgcn_mfma_f32_16x16x32_bf16(av, bv[ct], zero, 0, 0, 0);
            float m = fmaxf(fmaxf(a[0], a[1]), fmaxf(a[2], a[3]));
            m = fmaxf(m, __shfl_xor(m, 16));
            m = fmaxf(m, __shfl_xor(m, 32));
            if (lane < 16) {
                const int d = ct * 16 + lane;
                const float val = m * ngs[d] + nbs[d];
                f[(size_t)gp * 96 + d] = val;
                fbf[(size_t)gp * 96 + d] = __float2bfloat16(val);
            }
        }
    }
}

// ---------------------------------------------------------------------------
// MFMA GEMM: D = A[M,K]bf16 @ Bt[N,K]bf16^T, tile 64 x (16*NT), 4 waves.
// MODE 0: bfout = bf16(gelu(acc + bias[col]))            (MLP layer 1 -> h)
// MODE 1: f += acc*g+b; fout=f, bfout=bf16(f)            (MLP layer 2)
// MODE 2: fout = acc                                     (LFP projection -> y)
// MODE 3: fout = acc + bias[col]                         (head, BN pre-folded)
// ---------------------------------------------------------------------------
template <int MODE, int NT>
__global__ __launch_bounds__(256) void mfma_gemm(
    const __hip_bfloat16* __restrict__ A,
    const __hip_bfloat16* __restrict__ Bt,
    const float* __restrict__ bias,
    const float* __restrict__ g, const float* __restrict__ bvec,
    float* __restrict__ fout,
    __hip_bfloat16* __restrict__ bfout,
    int K, int N)
{
    constexpr int BN = 16 * NT;
    __shared__ short As[64][40];
    __shared__ short Bs[BN][40];

    const int tid  = threadIdx.x;
    const int wave = tid >> 6;
    const int lane = tid & 63;
    const int row0 = blockIdx.y * 64;
    const int c0   = blockIdx.x * BN;

    f32x4 acc[NT];
#pragma unroll
    for (int i = 0; i < NT; ++i) acc[i] = f32x4{0.f, 0.f, 0.f, 0.f};

    const int sr = tid >> 2;
    const int sk = (tid & 3) * 8;
    const short* Ag = (const short*)A;
    const short* Bg = (const short*)Bt;

    for (int k0 = 0; k0 < K; k0 += 32) {
        *(bf16x8*)&As[sr][sk] =
            *(const bf16x8*)&Ag[(size_t)(row0 + sr) * K + k0 + sk];
        for (int idx = tid; idx < BN * 4; idx += 256) {
            const int r = idx >> 2, ko = (idx & 3) * 8;
            *(bf16x8*)&Bs[r][ko] =
                *(const bf16x8*)&Bg[(size_t)(c0 + r) * K + k0 + ko];
        }
        __syncthreads();

        const int kc = (lane >> 4) * 8;
        const bf16x8 av = *(const bf16x8*)&As[wave * 16 + (lane & 15)][kc];
#pragma unroll
        for (int ct = 0; ct < NT; ++ct) {
            const bf16x8 bv = *(const bf16x8*)&Bs[ct * 16 + (lane & 15)][kc];
            acc[ct] = __builtin_amdgcn_mfma_f32_16x16x32_bf16(av, bv, acc[ct], 0, 0, 0);
        }
        __syncthreads();
    }

    const int erow = row0 + wave * 16 + ((lane >> 4) << 2);
    const int ecl  = lane & 15;
#pragma unroll
    for (int ct = 0; ct < NT; ++ct) {
        const int col = c0 + ct * 16 + ecl;
#pragma unroll
        for (int r = 0; r < 4; ++r) {
            const int row = erow + r;
            const float v = acc[ct][r];
            if (MODE == 0) {
                bfout[(size_t)row * N + col] = __float2bfloat16(gelu_f(v + bias[col]));
            } else if (MODE == 1) {
                const size_t o = (size_t)row * N + col;
                const float nf = fout[o] + v * g[col] + bvec[col];
                fout[o] = nf;
                bfout[o] = __float2bfloat16(nf);
            } else if (MODE == 2) {
                fout[(size_t)row * N + col] = v;
            } else {
                fout[(size_t)row * N + col] = v + bias[col];
            }
        }
    }
}

// ---------------------------------------------------------------------------
// LFP gather-max:  f[p] += ( max_k y[knn[p][k]] - y[p] ) * g + b; emits bf16 f.
// ---------------------------------------------------------------------------
__global__ __launch_bounds__(256) void gathermax_kernel(
    const float* __restrict__ y, const int* __restrict__ knn,
    const float* __restrict__ g, const float* __restrict__ b,
    float* __restrict__ f, __hip_bfloat16* __restrict__ fbf)
{
    __shared__ int knns[16][16];
    const int tid = threadIdx.x;
    const int pl  = tid >> 4;
    const int t   = tid & 15;
    const int p0  = blockIdx.x * 16;
    knns[pl][t] = knn[(p0 + pl) * KNB + t];
    __syncthreads();

    const int p   = p0 + pl;
    const int off = t * 6;

    float m[6];
#pragma unroll
    for (int i = 0; i < 6; ++i) m[i] = -INFINITY;

#pragma unroll 4
    for (int k = 0; k < 16; ++k) {
        const int j = knns[pl][k];
        const float* yr = y + (size_t)j * 96 + off;
        const float2 v0 = *(const float2*)(yr + 0);
        const float2 v1 = *(const float2*)(yr + 2);
        const float2 v2 = *(const float2*)(yr + 4);
        m[0] = fmaxf(m[0], v0.x); m[1] = fmaxf(m[1], v0.y);
        m[2] = fmaxf(m[2], v1.x); m[3] = fmaxf(m[3], v1.y);
        m[4] = fmaxf(m[4], v2.x); m[5] = fmaxf(m[5], v2.y);
    }

    const float* yc = y + (size_t)p * 96 + off;
    float* fr = f + (size_t)p * 96 + off;
    __hip_bfloat16* fbr = fbf + (size_t)p * 96 + off;
#pragma unroll
    for (int i = 0; i < 6; ++i) {
        const float nf = fr[i] + (m[i] - yc[i]) * g[off + i] + b[off + i];
        fr[i] = nf;
        fbr[i] = __float2bfloat16(nf);
    }
}

// ---------------------------------------------------------------------------
extern "C" void kernel_launch(void* const* d_in, const int* in_sizes, int n_in,
                              void* d_out, int out_size, void* d_ws, size_t ws_size,
                              hipStream_t stream)
{
    const float* x     = (const float*)d_in[0];
    const float* xyz   = (const float*)d_in[1];
    const int*   knn   = (const int*)d_in[2];
    const float* ne_w1 = (const float*)d_in[3];
    const float* ne_g1 = (const float*)d_in[4];
    const float* ne_b1 = (const float*)d_in[5];
    const float* ne_w2 = (const float*)d_in[6];
    const float* ne_g2 = (const float*)d_in[7];
    const float* ne_b2 = (const float*)d_in[8];
    const float* ne_w3 = (const float*)d_in[9];
    const float* nbr_g = (const float*)d_in[10];
    const float* nbr_b = (const float*)d_in[11];
    const float* m0_w1 = (const float*)d_in[12];
    const float* m0_b1 = (const float*)d_in[13];
    const float* m0_w2 = (const float*)d_in[14];
    const float* m0_g  = (const float*)d_in[15];
    const float* m0_b  = (const float*)d_in[16];
    const float* lfp_w = (const float*)d_in[17];
    const float* lfp_g = (const float*)d_in[18];
    const float* lfp_b = (const float*)d_in[19];
    const float* ms_w1 = (const float*)d_in[20];
    const float* ms_b1 = (const float*)d_in[21];
    const float* ms_w2 = (const float*)d_in[22];
    const float* ms_g  = (const float*)d_in[23];
    const float* ms_b  = (const float*)d_in[24];
    const float* pp_g  = (const float*)d_in[25];
    const float* pp_b  = (const float*)d_in[26];
    const float* pp_w  = (const float*)d_in[27];

    float* out = (float*)d_out;

    // --- workspace layout (all 16B-aligned) ---
    float* f   = (float*)d_ws;                            // [N][96] f32
    float* y   = f + (size_t)NPTS * 96;                   // [N][96] f32
    __hip_bfloat16* fbf = (__hip_bfloat16*)(y + (size_t)NPTS * 96);  // [N][96] bf16
    __hip_bfloat16* h   = fbf + (size_t)NPTS * 96;        // [N][384] bf16
    __hip_bfloat16* w_m0w1t = h + (size_t)NPTS * 384;     // [384][96]
    __hip_bfloat16* w_m0w2t = w_m0w1t + 36864;            // [96][384]
    __hip_bfloat16* w_msw1t = w_m0w2t + 36864;            // 2x[384][96]
    __hip_bfloat16* w_msw2t = w_msw1t + 2 * 36864;        // 2x[96][384]
    __hip_bfloat16* w_lfpt  = w_msw2t + 2 * 36864;        // 4x[96][96]
    __hip_bfloat16* w_ppt   = w_lfpt + 4 * 9216;          // [256][96]
    float* c_pp = (float*)(w_ppt + 24576);                // [256] f32

    prep_weights<<<1105, 256, 0, stream>>>(
        m0_w1, m0_w2, ms_w1, ms_w2, lfp_w, pp_w, pp_g, pp_b,
        w_m0w1t, w_m0w2t, w_msw1t, w_msw2t, w_lfpt, w_ppt, c_pp);

    ne_kernel<<<NPTS / 16, 256, 0, stream>>>(x, xyz, knn,
        ne_w1, ne_g1, ne_b1, ne_w2, ne_g2, ne_b2, ne_w3, nbr_g, nbr_b, f, fbf);

    auto mlp = [&](const __hip_bfloat16* w1t, const float* b1,
                   const __hip_bfloat16* w2t, const float* gg, const float* bb) {
        mfma_gemm<0, 4><<<dim3(6, NPTS / 64), 256, 0, stream>>>(
            fbf, w1t, b1, nullptr, nullptr, nullptr, h, 96, 384);
        mfma_gemm<1, 6><<<dim3(1, NPTS / 64), 256, 0, stream>>>(
            h, w2t, nullptr, gg, bb, f, fbf, 384, 96);
    };

    mlp(w_m0w1t, m0_b1, w_m0w2t, m0_g, m0_b);

    for (int i = 0; i < 4; ++i) {
        mfma_gemm<2, 6><<<dim3(1, NPTS / 64), 256, 0, stream>>>(
            fbf, w_lfpt + (size_t)i * 9216, nullptr, nullptr, nullptr, y, nullptr, 96, 96);
        gathermax_kernel<<<NPTS / 16, 256, 0, stream>>>(
            y, knn, lfp_g + i * 96, lfp_b + i * 96, f, fbf);
        if (i & 1) {
            const int jj = i / 2;
            mlp(w_msw1t + (size_t)jj * 36864, ms_b1 + (size_t)jj * 384,
                w_msw2t + (size_t)jj * 36864, ms_g + jj * 96, ms_b + jj * 96);
        }
    }

    mfma_gemm<3, 4><<<dim3(4, NPTS / 64), 256, 0, stream>>>(
        fbf, w_ppt, c_pp, nullptr, nullptr, out, nullptr, 96, 256);
}

// Round 5
// 679.278 us; speedup vs baseline: 1.8007x; 1.0145x over previous
//
#include <hip/hip_runtime.h>
#include <hip/hip_bf16.h>
#include <math.h>

#define NPTS 65536
#define KNB  16

typedef __attribute__((ext_vector_type(8))) short bf16x8;
typedef __attribute__((ext_vector_type(4))) float f32x4;

// Fast exact-grade GELU: erf via Abramowitz-Stegun 7.1.26 (|eps|<=1.5e-7),
// one v_exp + one v_rcp + 6 fma instead of libm erff's ~40+ inst w/ branches.
__device__ __forceinline__ float gelu_f(float v) {
    const float z  = v * 0.70710678118654752f;
    const float az = fabsf(z);
    const float t  = __builtin_amdgcn_rcpf(fmaf(0.3275911f, az, 1.0f));
    float p = fmaf(t, 1.061405429f, -1.453152027f);
    p = fmaf(t, p, 1.421413741f);
    p = fmaf(t, p, -0.284496736f);
    p = fmaf(t, p, 0.254829592f);
    p = p * t;
    const float e  = __expf(-z * z);
    float er = fmaf(-p, e, 1.0f);
    er = copysignf(er, z);
    return 0.5f * v * (1.0f + er);
}

__device__ __forceinline__ short f2bf_s(float v) {
    __hip_bfloat16 h = __float2bfloat16(v);
    return *reinterpret_cast<short*>(&h);
}

// ---------------------------------------------------------------------------
// Weight prep: transpose all GEMM weights to W^T [N][K] bf16. Head BN folded:
// bn(f)@W = f@(g*W) + (b@W); b@W precomputed into c_pp.
// ---------------------------------------------------------------------------
__global__ __launch_bounds__(256) void prep_weights(
    const float* __restrict__ m0_w1, const float* __restrict__ m0_w2,
    const float* __restrict__ ms_w1, const float* __restrict__ ms_w2,
    const float* __restrict__ lfp_w,
    const float* __restrict__ pp_w, const float* __restrict__ pp_g,
    const float* __restrict__ pp_b,
    __hip_bfloat16* __restrict__ w_m0w1t, __hip_bfloat16* __restrict__ w_m0w2t,
    __hip_bfloat16* __restrict__ w_msw1t, __hip_bfloat16* __restrict__ w_msw2t,
    __hip_bfloat16* __restrict__ w_lfpt,  __hip_bfloat16* __restrict__ w_ppt,
    float* __restrict__ c_pp)
{
    int idx = blockIdx.x * 256 + threadIdx.x;
    if (idx < 36864) {                       // m0_w1^T [384][96]
        int n = idx / 96, k = idx % 96;
        w_m0w1t[idx] = __float2bfloat16(m0_w1[k * 384 + n]);
        return;
    }
    idx -= 36864;
    if (idx < 36864) {                       // m0_w2^T [96][384]
        int n = idx / 384, k = idx % 384;
        w_m0w2t[idx] = __float2bfloat16(m0_w2[k * 96 + n]);
        return;
    }
    idx -= 36864;
    if (idx < 2 * 36864) {                   // ms_w1^T[j] [384][96]
        int j = idx / 36864, r = idx % 36864;
        int n = r / 96, k = r % 96;
        w_msw1t[idx] = __float2bfloat16(ms_w1[j * 36864 + k * 384 + n]);
        return;
    }
    idx -= 2 * 36864;
    if (idx < 2 * 36864) {                   // ms_w2^T[j] [96][384]
        int j = idx / 36864, r = idx % 36864;
        int n = r / 384, k = r % 384;
        w_msw2t[idx] = __float2bfloat16(ms_w2[j * 36864 + k * 96 + n]);
        return;
    }
    idx -= 2 * 36864;
    if (idx < 4 * 9216) {                    // lfp_w^T[i] [96][96]
        int i = idx / 9216, r = idx % 9216;
        int n = r / 96, k = r % 96;
        w_lfpt[idx] = __float2bfloat16(lfp_w[i * 9216 + k * 96 + n]);
        return;
    }
    idx -= 4 * 9216;
    if (idx < 24576) {                       // (pp_g * pp_w)^T [256][96]
        int n = idx / 96, k = idx % 96;
        w_ppt[idx] = __float2bfloat16(pp_g[k] * pp_w[k * 256 + n]);
        return;
    }
    idx -= 24576;
    if (idx < 256) {                         // c_pp[n] = sum_k pp_b[k]*pp_w[k][n]
        float s = 0.f;
        for (int k = 0; k < 96; ++k) s += pp_b[k] * pp_w[k * 256 + idx];
        c_pp[idx] = s;
    }
}

// ---------------------------------------------------------------------------
// Neighbor embedding, MFMA stages 2+3.
// Block = 256 threads = 16 points x 16 neighbors.
// Stage 1 per-edge fp32 VALU (7->16 + gelu) -> h16 bf16 in LDS [256][24].
// Stage 2 via 16x16x32 MFMA with K zero-padded 16->32: av upper-half lanes
//   use explicit zero frags, w2ts rows 16..31 are explicit zeros (no garbage
//   can enter the MFMA). BN+gelu applied on C-frag, repacked to h32s LDS.
// Stage 3 + neighbor-max via MFMA vs W3^T; maxpool = 4-reg max + shfl(16,32).
// ---------------------------------------------------------------------------
__global__ __launch_bounds__(256) void ne_kernel(
    const float* __restrict__ x, const float* __restrict__ xyz,
    const int* __restrict__ knn,
    const float* __restrict__ w1, const float* __restrict__ g1, const float* __restrict__ b1,
    const float* __restrict__ w2, const float* __restrict__ g2, const float* __restrict__ b2,
    const float* __restrict__ w3,
    const float* __restrict__ ng, const float* __restrict__ nb,
    float* __restrict__ f, __hip_bfloat16* __restrict__ fbf)
{
    __shared__ float w1s[7 * 16];
    __shared__ float g1s[16], b1s[16], g2s[32], b2s[32];
    __shared__ float ngs[96], nbs[96];
    __shared__ short h16s[256][24];   // k 0..15 data; 48B rows (16B aligned)
    __shared__ short w2ts[32][40];    // w2^T [out][k], k 16..31 explicit zero
    __shared__ short h32s[256][40];
    __shared__ short w3t[96][40];

    const int tid = threadIdx.x;
    for (int i = tid; i < 112; i += 256) w1s[i] = w1[i];
    for (int i = tid; i < 1280; i += 256) {          // w2ts incl. zero pad
        const int o = i / 40, kk = i % 40;
        w2ts[o][kk] = (kk < 16) ? f2bf_s(w2[kk * 32 + o]) : (short)0;
    }
    if (tid < 16) { g1s[tid] = g1[tid]; b1s[tid] = b1[tid]; }
    if (tid < 32) { g2s[tid] = g2[tid]; b2s[tid] = b2[tid]; }
    if (tid < 96) { ngs[tid] = ng[tid]; nbs[tid] = nb[tid]; }
    for (int i = tid; i < 3072; i += 256) {
        const int c = i / 96, n = i % 96;            // coalesced over n
        w3t[n][c] = f2bf_s(w3[i]);
    }
    __syncthreads();

    const int pl = tid >> 4;          // local point 0..15
    const int k  = tid & 15;          // neighbor
    const int p  = blockIdx.x * 16 + pl;
    const int j  = knn[p * KNB + k];

    float in7[7];
    {
        float cx0 = xyz[p * 3 + 0], cx1 = xyz[p * 3 + 1], cx2 = xyz[p * 3 + 2];
        in7[0] = xyz[j * 3 + 0] - cx0;
        in7[1] = xyz[j * 3 + 1] - cx1;
        in7[2] = xyz[j * 3 + 2] - cx2;
        in7[3] = x[j * 4 + 0];
        in7[4] = x[j * 4 + 1];
        in7[5] = x[j * 4 + 2];
        in7[6] = x[j * 4 + 3];
    }

    // --- stage 1 (VALU): 7 -> 16, bn, gelu ---
    {
        bf16x8 t0, t1;
#pragma unroll
        for (int o = 0; o < 16; ++o) {
            float s = 0.f;
#pragma unroll
            for (int c = 0; c < 7; ++c) s += in7[c] * w1s[c * 16 + o];
            const float hv = gelu_f(s * g1s[o] + b1s[o]);
            if (o < 8) t0[o] = f2bf_s(hv); else t1[o - 8] = f2bf_s(hv);
        }
        *(bf16x8*)&h16s[tid][0] = t0;
        *(bf16x8*)&h16s[tid][8] = t1;
    }
    __syncthreads();

    const int wave = tid >> 6;
    const int lane = tid & 63;
    const int lr   = lane & 15;
    const int kc   = (lane >> 4) * 8;
    const f32x4 zero = {0.f, 0.f, 0.f, 0.f};
    const bf16x8 zero8 = {0, 0, 0, 0, 0, 0, 0, 0};

    // --- stage 2 (MFMA, K zero-padded 16->32): 16 -> 32, bn, gelu ---
    {
        const float g2r0 = g2s[lr],      b2r0 = b2s[lr];
        const float g2r1 = g2s[16 + lr], b2r1 = b2s[16 + lr];
        const bf16x8 w2v0 = *(const bf16x8*)&w2ts[lr][kc];        // zeros for k>=16
        const bf16x8 w2v1 = *(const bf16x8*)&w2ts[16 + lr][kc];
#pragma unroll
        for (int pp = 0; pp < 4; ++pp) {
            const int lpl = wave * 4 + pp;
            bf16x8 av = zero8;
            if (lane < 32) av = *(const bf16x8*)&h16s[lpl * 16 + lr][kc];
            f32x4 c0 = __builtin_amdgcn_mfma_f32_16x16x32_bf16(av, w2v0, zero, 0, 0, 0);
            f32x4 c1 = __builtin_amdgcn_mfma_f32_16x16x32_bf16(av, w2v1, zero, 0, 0, 0);
#pragma unroll
            for (int r = 0; r < 4; ++r) {
                const int erow = lpl * 16 + (lane >> 4) * 4 + r;
                h32s[erow][lr]      = f2bf_s(gelu_f(fmaf(c0[r], g2r0, b2r0)));
                h32s[erow][16 + lr] = f2bf_s(gelu_f(fmaf(c1[r], g2r1, b2r1)));
            }
        }
    }
    __syncthreads();

    // --- stage 3 (MFMA) + neighbor max + BN ---
    bf16x8 bv[6];
#pragma unroll
    for (int ct = 0; ct < 6; ++ct)
        bv[ct] = *(const bf16x8*)&w3t[ct * 16 + lr][kc];

#pragma unroll
    for (int pp = 0; pp < 4; ++pp) {
        const int lpl = wave * 4 + pp;
        const int gp  = blockIdx.x * 16 + lpl;
        const bf16x8 av = *(const bf16x8*)&h32s[lpl * 16 + lr][kc];
#pragma unroll
        for (int ct = 0; ct < 6; ++ct) {
            f32x4 a = __builtin_amdgcn_mfma_f32_16x16x32_bf16(av, bv[ct], zero, 0, 0, 0);
            float m = fmaxf(fmaxf(a[0], a[1]), fmaxf(a[2], a[3]));
            m = fmaxf(m, __shfl_xor(m, 16));
            m = fmaxf(m, __shfl_xor(m, 32));
            if (lane < 16) {
                const int d = ct * 16 + lane;
                const float val = m * ngs[d] + nbs[d];
                f[(size_t)gp * 96 + d] = val;
                fbf[(size_t)gp * 96 + d] = __float2bfloat16(val);
            }
        }
    }
}

// ---------------------------------------------------------------------------
// MFMA GEMM: D = A[M,K]bf16 @ Bt[N,K]bf16^T, tile 64 x (16*NT), 4 waves.
// MODE 0: bfout = bf16(gelu(acc + bias[col]))            (MLP layer 1 -> h)
// MODE 1: f += acc*g+b; fout=f, bfout=bf16(f)            (MLP layer 2)
// MODE 2: fout = acc                                     (LFP projection -> y)
// MODE 3: fout = acc + bias[col]                         (head, BN pre-folded)
// ---------------------------------------------------------------------------
template <int MODE, int NT>
__global__ __launch_bounds__(256) void mfma_gemm(
    const __hip_bfloat16* __restrict__ A,
    const __hip_bfloat16* __restrict__ Bt,
    const float* __restrict__ bias,
    const float* __restrict__ g, const float* __restrict__ bvec,
    float* __restrict__ fout,
    __hip_bfloat16* __restrict__ bfout,
    int K, int N)
{
    constexpr int BN = 16 * NT;
    __shared__ short As[64][40];
    __shared__ short Bs[BN][40];

    const int tid  = threadIdx.x;
    const int wave = tid >> 6;
    const int lane = tid & 63;
    const int row0 = blockIdx.y * 64;
    const int c0   = blockIdx.x * BN;

    f32x4 acc[NT];
#pragma unroll
    for (int i = 0; i < NT; ++i) acc[i] = f32x4{0.f, 0.f, 0.f, 0.f};

    const int sr = tid >> 2;
    const int sk = (tid & 3) * 8;
    const short* Ag = (const short*)A;
    const short* Bg = (const short*)Bt;

    for (int k0 = 0; k0 < K; k0 += 32) {
        *(bf16x8*)&As[sr][sk] =
            *(const bf16x8*)&Ag[(size_t)(row0 + sr) * K + k0 + sk];
        for (int idx = tid; idx < BN * 4; idx += 256) {
            const int r = idx >> 2, ko = (idx & 3) * 8;
            *(bf16x8*)&Bs[r][ko] =
                *(const bf16x8*)&Bg[(size_t)(c0 + r) * K + k0 + ko];
        }
        __syncthreads();

        const int kc = (lane >> 4) * 8;
        const bf16x8 av = *(const bf16x8*)&As[wave * 16 + (lane & 15)][kc];
#pragma unroll
        for (int ct = 0; ct < NT; ++ct) {
            const bf16x8 bv = *(const bf16x8*)&Bs[ct * 16 + (lane & 15)][kc];
            acc[ct] = __builtin_amdgcn_mfma_f32_16x16x32_bf16(av, bv, acc[ct], 0, 0, 0);
        }
        __syncthreads();
    }

    const int erow = row0 + wave * 16 + ((lane >> 4) << 2);
    const int ecl  = lane & 15;
#pragma unroll
    for (int ct = 0; ct < NT; ++ct) {
        const int col = c0 + ct * 16 + ecl;
#pragma unroll
        for (int r = 0; r < 4; ++r) {
            const int row = erow + r;
            const float v = acc[ct][r];
            if (MODE == 0) {
                bfout[(size_t)row * N + col] = __float2bfloat16(gelu_f(v + bias[col]));
            } else if (MODE == 1) {
                const size_t o = (size_t)row * N + col;
                const float nf = fout[o] + v * g[col] + bvec[col];
                fout[o] = nf;
                bfout[o] = __float2bfloat16(nf);
            } else if (MODE == 2) {
                fout[(size_t)row * N + col] = v;
            } else {
                fout[(size_t)row * N + col] = v + bias[col];
            }
        }
    }
}

// ---------------------------------------------------------------------------
// LFP gather-max:  f[p] += ( max_k y[knn[p][k]] - y[p] ) * g + b; emits bf16 f.
// ---------------------------------------------------------------------------
__global__ __launch_bounds__(256) void gathermax_kernel(
    const float* __restrict__ y, const int* __restrict__ knn,
    const float* __restrict__ g, const float* __restrict__ b,
    float* __restrict__ f, __hip_bfloat16* __restrict__ fbf)
{
    __shared__ int knns[16][16];
    const int tid = threadIdx.x;
    const int pl  = tid >> 4;
    const int t   = tid & 15;
    const int p0  = blockIdx.x * 16;
    knns[pl][t] = knn[(p0 + pl) * KNB + t];
    __syncthreads();

    const int p   = p0 + pl;
    const int off = t * 6;

    float m[6];
#pragma unroll
    for (int i = 0; i < 6; ++i) m[i] = -INFINITY;

#pragma unroll 4
    for (int k = 0; k < 16; ++k) {
        const int j = knns[pl][k];
        const float* yr = y + (size_t)j * 96 + off;
        const float2 v0 = *(const float2*)(yr + 0);
        const float2 v1 = *(const float2*)(yr + 2);
        const float2 v2 = *(const float2*)(yr + 4);
        m[0] = fmaxf(m[0], v0.x); m[1] = fmaxf(m[1], v0.y);
        m[2] = fmaxf(m[2], v1.x); m[3] = fmaxf(m[3], v1.y);
        m[4] = fmaxf(m[4], v2.x); m[5] = fmaxf(m[5], v2.y);
    }

    const float* yc = y + (size_t)p * 96 + off;
    float* fr = f + (size_t)p * 96 + off;
    __hip_bfloat16* fbr = fbf + (size_t)p * 96 + off;
#pragma unroll
    for (int i = 0; i < 6; ++i) {
        const float nf = fr[i] + (m[i] - yc[i]) * g[off + i] + b[off + i];
        fr[i] = nf;
        fbr[i] = __float2bfloat16(nf);
    }
}

// ---------------------------------------------------------------------------
extern "C" void kernel_launch(void* const* d_in, const int* in_sizes, int n_in,
                              void* d_out, int out_size, void* d_ws, size_t ws_size,
                              hipStream_t stream)
{
    const float* x     = (const float*)d_in[0];
    const float* xyz   = (const float*)d_in[1];
    const int*   knn   = (const int*)d_in[2];
    const float* ne_w1 = (const float*)d_in[3];
    const float* ne_g1 = (const float*)d_in[4];
    const float* ne_b1 = (const float*)d_in[5];
    const float* ne_w2 = (const float*)d_in[6];
    const float* ne_g2 = (const float*)d_in[7];
    const float* ne_b2 = (const float*)d_in[8];
    const float* ne_w3 = (const float*)d_in[9];
    const float* nbr_g = (const float*)d_in[10];
    const float* nbr_b = (const float*)d_in[11];
    const float* m0_w1 = (const float*)d_in[12];
    const float* m0_b1 = (const float*)d_in[13];
    const float* m0_w2 = (const float*)d_in[14];
    const float* m0_g  = (const float*)d_in[15];
    const float* m0_b  = (const float*)d_in[16];
    const float* lfp_w = (const float*)d_in[17];
    const float* lfp_g = (const float*)d_in[18];
    const float* lfp_b = (const float*)d_in[19];
    const float* ms_w1 = (const float*)d_in[20];
    const float* ms_b1 = (const float*)d_in[21];
    const float* ms_w2 = (const float*)d_in[22];
    const float* ms_g  = (const float*)d_in[23];
    const float* ms_b  = (const float*)d_in[24];
    const float* pp_g  = (const float*)d_in[25];
    const float* pp_b  = (const float*)d_in[26];
    const float* pp_w  = (const float*)d_in[27];

    float* out = (float*)d_out;

    // --- workspace layout (all 16B-aligned) ---
    float* f   = (float*)d_ws;                            // [N][96] f32
    float* y   = f + (size_t)NPTS * 96;                   // [N][96] f32
    __hip_bfloat16* fbf = (__hip_bfloat16*)(y + (size_t)NPTS * 96);  // [N][96] bf16
    __hip_bfloat16* h   = fbf + (size_t)NPTS * 96;        // [N][384] bf16
    __hip_bfloat16* w_m0w1t = h + (size_t)NPTS * 384;     // [384][96]
    __hip_bfloat16* w_m0w2t = w_m0w1t + 36864;            // [96][384]
    __hip_bfloat16* w_msw1t = w_m0w2t + 36864;            // 2x[384][96]
    __hip_bfloat16* w_msw2t = w_msw1t + 2 * 36864;        // 2x[96][384]
    __hip_bfloat16* w_lfpt  = w_msw2t + 2 * 36864;        // 4x[96][96]
    __hip_bfloat16* w_ppt   = w_lfpt + 4 * 9216;          // [256][96]
    float* c_pp = (float*)(w_ppt + 24576);                // [256] f32

    prep_weights<<<1105, 256, 0, stream>>>(
        m0_w1, m0_w2, ms_w1, ms_w2, lfp_w, pp_w, pp_g, pp_b,
        w_m0w1t, w_m0w2t, w_msw1t, w_msw2t, w_lfpt, w_ppt, c_pp);

    ne_kernel<<<NPTS / 16, 256, 0, stream>>>(x, xyz, knn,
        ne_w1, ne_g1, ne_b1, ne_w2, ne_g2, ne_b2, ne_w3, nbr_g, nbr_b, f, fbf);

    auto mlp = [&](const __hip_bfloat16* w1t, const float* b1,
                   const __hip_bfloat16* w2t, const float* gg, const float* bb) {
        mfma_gemm<0, 4><<<dim3(6, NPTS / 64), 256, 0, stream>>>(
            fbf, w1t, b1, nullptr, nullptr, nullptr, h, 96, 384);
        mfma_gemm<1, 6><<<dim3(1, NPTS / 64), 256, 0, stream>>>(
            h, w2t, nullptr, gg, bb, f, fbf, 384, 96);
    };

    mlp(w_m0w1t, m0_b1, w_m0w2t, m0_g, m0_b);

    for (int i = 0; i < 4; ++i) {
        mfma_gemm<2, 6><<<dim3(1, NPTS / 64), 256, 0, stream>>>(
            fbf, w_lfpt + (size_t)i * 9216, nullptr, nullptr, nullptr, y, nullptr, 96, 96);
        gathermax_kernel<<<NPTS / 16, 256, 0, stream>>>(
            y, knn, lfp_g + i * 96, lfp_b + i * 96, f, fbf);
        if (i & 1) {
            const int jj = i / 2;
            mlp(w_msw1t + (size_t)jj * 36864, ms_b1 + (size_t)jj * 384,
                w_msw2t + (size_t)jj * 36864, ms_g + jj * 96, ms_b + jj * 96);
        }
    }

    mfma_gemm<3, 4><<<dim3(4, NPTS / 64), 256, 0, stream>>>(
        fbf, w_ppt, c_pp, nullptr, nullptr, out, nullptr, 96, 256);
}

// Round 7
// 600.347 us; speedup vs baseline: 2.0374x; 1.1315x over previous
//
#include <hip/hip_runtime.h>
#include <hip/hip_bf16.h>
#include <math.h>

#define NPTS 65536
#define KNB  16

typedef __attribute__((ext_vector_type(8))) short bf16x8;
typedef __attribute__((ext_vector_type(4))) float f32x4;

// Fast exact-grade GELU: erf via Abramowitz-Stegun 7.1.26 (|eps|<=1.5e-7).
__device__ __forceinline__ float gelu_f(float v) {
    const float z  = v * 0.70710678118654752f;
    const float az = fabsf(z);
    const float t  = __builtin_amdgcn_rcpf(fmaf(0.3275911f, az, 1.0f));
    float p = fmaf(t, 1.061405429f, -1.453152027f);
    p = fmaf(t, p, 1.421413741f);
    p = fmaf(t, p, -0.284496736f);
    p = fmaf(t, p, 0.254829592f);
    p = p * t;
    const float e  = __expf(-z * z);
    float er = fmaf(-p, e, 1.0f);
    er = copysignf(er, z);
    return 0.5f * v * (1.0f + er);
}

__device__ __forceinline__ short f2bf_s(float v) {
    __hip_bfloat16 h = __float2bfloat16(v);
    return *reinterpret_cast<short*>(&h);
}

// ---------------------------------------------------------------------------
// Weight prep: transpose all GEMM weights to W^T [N][K] bf16. Head BN folded:
// bn(f)@W = f@(g*W) + (b@W); b@W precomputed into c_pp.
// ---------------------------------------------------------------------------
__global__ __launch_bounds__(256) void prep_weights(
    const float* __restrict__ m0_w1, const float* __restrict__ m0_w2,
    const float* __restrict__ ms_w1, const float* __restrict__ ms_w2,
    const float* __restrict__ lfp_w,
    const float* __restrict__ pp_w, const float* __restrict__ pp_g,
    const float* __restrict__ pp_b,
    __hip_bfloat16* __restrict__ w_m0w1t, __hip_bfloat16* __restrict__ w_m0w2t,
    __hip_bfloat16* __restrict__ w_msw1t, __hip_bfloat16* __restrict__ w_msw2t,
    __hip_bfloat16* __restrict__ w_lfpt,  __hip_bfloat16* __restrict__ w_ppt,
    float* __restrict__ c_pp)
{
    int idx = blockIdx.x * 256 + threadIdx.x;
    if (idx < 36864) {                       // m0_w1^T [384][96]
        int n = idx / 96, k = idx % 96;
        w_m0w1t[idx] = __float2bfloat16(m0_w1[k * 384 + n]);
        return;
    }
    idx -= 36864;
    if (idx < 36864) {                       // m0_w2^T [96][384]
        int n = idx / 384, k = idx % 384;
        w_m0w2t[idx] = __float2bfloat16(m0_w2[k * 96 + n]);
        return;
    }
    idx -= 36864;
    if (idx < 2 * 36864) {                   // ms_w1^T[j] [384][96]
        int j = idx / 36864, r = idx % 36864;
        int n = r / 96, k = r % 96;
        w_msw1t[idx] = __float2bfloat16(ms_w1[j * 36864 + k * 384 + n]);
        return;
    }
    idx -= 2 * 36864;
    if (idx < 2 * 36864) {                   // ms_w2^T[j] [96][384]
        int j = idx / 36864, r = idx % 36864;
        int n = r / 384, k = r % 384;
        w_msw2t[idx] = __float2bfloat16(ms_w2[j * 36864 + k * 96 + n]);
        return;
    }
    idx -= 2 * 36864;
    if (idx < 4 * 9216) {                    // lfp_w^T[i] [96][96]
        int i = idx / 9216, r = idx % 9216;
        int n = r / 96, k = r % 96;
        w_lfpt[idx] = __float2bfloat16(lfp_w[i * 9216 + k * 96 + n]);
        return;
    }
    idx -= 4 * 9216;
    if (idx < 24576) {                       // (pp_g * pp_w)^T [256][96]
        int n = idx / 96, k = idx % 96;
        w_ppt[idx] = __float2bfloat16(pp_g[k] * pp_w[k * 256 + n]);
        return;
    }
    idx -= 24576;
    if (idx < 256) {                         // c_pp[n] = sum_k pp_b[k]*pp_w[k][n]
        float s = 0.f;
        for (int k = 0; k < 96; ++k) s += pp_b[k] * pp_w[k * 256 + idx];
        c_pp[idx] = s;
    }
}

// ---------------------------------------------------------------------------
// Neighbor embedding, MFMA stages 2+3.
// ---------------------------------------------------------------------------
__global__ __launch_bounds__(256) void ne_kernel(
    const float* __restrict__ x, const float* __restrict__ xyz,
    const int* __restrict__ knn,
    const float* __restrict__ w1, const float* __restrict__ g1, const float* __restrict__ b1,
    const float* __restrict__ w2, const float* __restrict__ g2, const float* __restrict__ b2,
    const float* __restrict__ w3,
    const float* __restrict__ ng, const float* __restrict__ nb,
    float* __restrict__ f, __hip_bfloat16* __restrict__ fbf)
{
    __shared__ float w1s[7 * 16];
    __shared__ float g1s[16], b1s[16], g2s[32], b2s[32];
    __shared__ float ngs[96], nbs[96];
    __shared__ short h16s[256][24];
    __shared__ short w2ts[32][40];
    __shared__ short h32s[256][40];
    __shared__ short w3t[96][40];

    const int tid = threadIdx.x;
    for (int i = tid; i < 112; i += 256) w1s[i] = w1[i];
    for (int i = tid; i < 1280; i += 256) {
        const int o = i / 40, kk = i % 40;
        w2ts[o][kk] = (kk < 16) ? f2bf_s(w2[kk * 32 + o]) : (short)0;
    }
    if (tid < 16) { g1s[tid] = g1[tid]; b1s[tid] = b1[tid]; }
    if (tid < 32) { g2s[tid] = g2[tid]; b2s[tid] = b2[tid]; }
    if (tid < 96) { ngs[tid] = ng[tid]; nbs[tid] = nb[tid]; }
    for (int i = tid; i < 3072; i += 256) {
        const int c = i / 96, n = i % 96;
        w3t[n][c] = f2bf_s(w3[i]);
    }
    __syncthreads();

    const int pl = tid >> 4;
    const int k  = tid & 15;
    const int p  = blockIdx.x * 16 + pl;
    const int j  = knn[p * KNB + k];

    float in7[7];
    {
        float cx0 = xyz[p * 3 + 0], cx1 = xyz[p * 3 + 1], cx2 = xyz[p * 3 + 2];
        in7[0] = xyz[j * 3 + 0] - cx0;
        in7[1] = xyz[j * 3 + 1] - cx1;
        in7[2] = xyz[j * 3 + 2] - cx2;
        in7[3] = x[j * 4 + 0];
        in7[4] = x[j * 4 + 1];
        in7[5] = x[j * 4 + 2];
        in7[6] = x[j * 4 + 3];
    }

    {
        bf16x8 t0, t1;
#pragma unroll
        for (int o = 0; o < 16; ++o) {
            float s = 0.f;
#pragma unroll
            for (int c = 0; c < 7; ++c) s += in7[c] * w1s[c * 16 + o];
            const float hv = gelu_f(s * g1s[o] + b1s[o]);
            if (o < 8) t0[o] = f2bf_s(hv); else t1[o - 8] = f2bf_s(hv);
        }
        *(bf16x8*)&h16s[tid][0] = t0;
        *(bf16x8*)&h16s[tid][8] = t1;
    }
    __syncthreads();

    const int wave = tid >> 6;
    const int lane = tid & 63;
    const int lr   = lane & 15;
    const int kc   = (lane >> 4) * 8;
    const f32x4 zero = {0.f, 0.f, 0.f, 0.f};
    const bf16x8 zero8 = {0, 0, 0, 0, 0, 0, 0, 0};

    {
        const float g2r0 = g2s[lr],      b2r0 = b2s[lr];
        const float g2r1 = g2s[16 + lr], b2r1 = b2s[16 + lr];
        const bf16x8 w2v0 = *(const bf16x8*)&w2ts[lr][kc];
        const bf16x8 w2v1 = *(const bf16x8*)&w2ts[16 + lr][kc];
#pragma unroll
        for (int pp = 0; pp < 4; ++pp) {
            const int lpl = wave * 4 + pp;
            bf16x8 av = zero8;
            if (lane < 32) av = *(const bf16x8*)&h16s[lpl * 16 + lr][kc];
            f32x4 c0 = __builtin_amdgcn_mfma_f32_16x16x32_bf16(av, w2v0, zero, 0, 0, 0);
            f32x4 c1 = __builtin_amdgcn_mfma_f32_16x16x32_bf16(av, w2v1, zero, 0, 0, 0);
#pragma unroll
            for (int r = 0; r < 4; ++r) {
                const int erow = lpl * 16 + (lane >> 4) * 4 + r;
                h32s[erow][lr]      = f2bf_s(gelu_f(fmaf(c0[r], g2r0, b2r0)));
                h32s[erow][16 + lr] = f2bf_s(gelu_f(fmaf(c1[r], g2r1, b2r1)));
            }
        }
    }
    __syncthreads();

    bf16x8 bv[6];
#pragma unroll
    for (int ct = 0; ct < 6; ++ct)
        bv[ct] = *(const bf16x8*)&w3t[ct * 16 + lr][kc];

#pragma unroll
    for (int pp = 0; pp < 4; ++pp) {
        const int lpl = wave * 4 + pp;
        const int gp  = blockIdx.x * 16 + lpl;
        const bf16x8 av = *(const bf16x8*)&h32s[lpl * 16 + lr][kc];
#pragma unroll
        for (int ct = 0; ct < 6; ++ct) {
            f32x4 a = __builtin_amdgcn_mfma_f32_16x16x32_bf16(av, bv[ct], zero, 0, 0, 0);
            float m = fmaxf(fmaxf(a[0], a[1]), fmaxf(a[2], a[3]));
            m = fmaxf(m, __shfl_xor(m, 16));
            m = fmaxf(m, __shfl_xor(m, 32));
            if (lane < 16) {
                const int d = ct * 16 + lane;
                const float val = m * ngs[d] + nbs[d];
                f[(size_t)gp * 96 + d] = val;
                fbf[(size_t)gp * 96 + d] = __float2bfloat16(val);
            }
        }
    }
}

// ---------------------------------------------------------------------------
// Fused MLP: f += bn(gelu(f@W1+b1)@W2).  Block = 64 rows, 4 waves.
// A (f rows, K=96) LDS-resident; h never hits global: each 64-col tile of h
// (= one K-chunk of layer 2) lives in a 64x64 LDS chunk, immediately consumed.
// w1t: [384][96] bf16; w2t: [96][384] bf16.
// ---------------------------------------------------------------------------
__global__ __launch_bounds__(256) void mlp_fused(
    const __hip_bfloat16* __restrict__ w1t, const float* __restrict__ b1,
    const __hip_bfloat16* __restrict__ w2t,
    const float* __restrict__ g, const float* __restrict__ b,
    float* __restrict__ f, __hip_bfloat16* __restrict__ fbf)
{
    __shared__ short As[64 * 104];     // f tile, K=96 resident (stride 104)
    __shared__ short Hs[64 * 72];      // h chunk 64x64 (stride 72)
    __shared__ short Bs[6912];         // W slice: [64][104] (L1) / [96][72] (L2)
    __shared__ float bias_s[384];
    __shared__ float gs[96], bs[96];

    const int tid  = threadIdx.x;
    const int wave = tid >> 6;
    const int lane = tid & 63;
    const int lr   = lane & 15;
    const int kc   = (lane >> 4) * 8;
    const int row0 = blockIdx.x * 64;

    const short* fb = (const short*)fbf;
    const short* w1 = (const short*)w1t;
    const short* w2 = (const short*)w2t;

    // stage A (64x96) + biases
    {
        const int sr = tid >> 2, sk = (tid & 3) * 8;
#pragma unroll
        for (int i = 0; i < 3; ++i)
            *(bf16x8*)&As[sr * 104 + sk + 32 * i] =
                *(const bf16x8*)&fb[(size_t)(row0 + sr) * 96 + sk + 32 * i];
        for (int i = tid; i < 384; i += 256) bias_s[i] = b1[i];
        if (tid < 96) { gs[tid] = g[tid]; bs[tid] = b[tid]; }
    }

    f32x4 acc2[6];
#pragma unroll
    for (int i = 0; i < 6; ++i) acc2[i] = f32x4{0.f, 0.f, 0.f, 0.f};

    for (int c = 0; c < 6; ++c) {
        // ---- stage W1^T slice: rows c*64..c*64+64, all 96 k ----
        __syncthreads();
        {
            const int sr = tid >> 2, sk = (tid & 3) * 8;
#pragma unroll
            for (int i = 0; i < 3; ++i)
                *(bf16x8*)&Bs[sr * 104 + sk + 32 * i] =
                    *(const bf16x8*)&w1[(size_t)(c * 64 + sr) * 96 + sk + 32 * i];
        }
        __syncthreads();

        // ---- layer 1: h_chunk = gelu(A @ W1_slice^T + b1) ----
        {
            f32x4 acc1[4];
#pragma unroll
            for (int i = 0; i < 4; ++i) acc1[i] = f32x4{0.f, 0.f, 0.f, 0.f};
#pragma unroll
            for (int k0 = 0; k0 < 96; k0 += 32) {
                const bf16x8 av = *(const bf16x8*)&As[(wave * 16 + lr) * 104 + k0 + kc];
#pragma unroll
                for (int ct = 0; ct < 4; ++ct) {
                    const bf16x8 bv = *(const bf16x8*)&Bs[(ct * 16 + lr) * 104 + k0 + kc];
                    acc1[ct] = __builtin_amdgcn_mfma_f32_16x16x32_bf16(av, bv, acc1[ct], 0, 0, 0);
                }
            }
            const int er = wave * 16 + ((lane >> 4) << 2);
#pragma unroll
            for (int ct = 0; ct < 4; ++ct) {
                const int cl = ct * 16 + lr;
                const float bb1 = bias_s[c * 64 + cl];
#pragma unroll
                for (int r = 0; r < 4; ++r)
                    Hs[(er + r) * 72 + cl] = f2bf_s(gelu_f(acc1[ct][r] + bb1));
            }
        }
        __syncthreads();

        // ---- stage W2^T chunk: 96 rows x k-cols c*64..c*64+64 ----
        {
            for (int i = tid; i < 768; i += 256) {
                const int r = i >> 3, ko = (i & 7) * 8;
                *(bf16x8*)&Bs[r * 72 + ko] =
                    *(const bf16x8*)&w2[(size_t)r * 384 + c * 64 + ko];
            }
        }
        __syncthreads();

        // ---- layer 2 partial: acc2 += h_chunk @ W2_chunk^T ----
#pragma unroll
        for (int ks = 0; ks < 64; ks += 32) {
            const bf16x8 av = *(const bf16x8*)&Hs[(wave * 16 + lr) * 72 + ks + kc];
#pragma unroll
            for (int ct = 0; ct < 6; ++ct) {
                const bf16x8 bv = *(const bf16x8*)&Bs[(ct * 16 + lr) * 72 + ks + kc];
                acc2[ct] = __builtin_amdgcn_mfma_f32_16x16x32_bf16(av, bv, acc2[ct], 0, 0, 0);
            }
        }
    }

    // ---- epilogue: f += acc2*g + b ----
    const int er = wave * 16 + ((lane >> 4) << 2);
#pragma unroll
    for (int ct = 0; ct < 6; ++ct) {
        const int col = ct * 16 + lr;
        const float gg = gs[col], bb = bs[col];
#pragma unroll
        for (int r = 0; r < 4; ++r) {
            const size_t o = (size_t)(row0 + er + r) * 96 + col;
            const float nf = f[o] + acc2[ct][r] * gg + bb;
            f[o] = nf;
            fbf[o] = __float2bfloat16(nf);
        }
    }
}

// ---------------------------------------------------------------------------
// LFP projection: y = f @ lfp_w  (A and full W LDS-resident, one sync).
// wT: [96][96] bf16.
// ---------------------------------------------------------------------------
__global__ __launch_bounds__(256) void proj_kernel(
    const __hip_bfloat16* __restrict__ fbf,
    const __hip_bfloat16* __restrict__ wT,
    float* __restrict__ y)
{
    __shared__ short As[64 * 104];
    __shared__ short Ws[96 * 104];

    const int tid  = threadIdx.x;
    const int wave = tid >> 6;
    const int lane = tid & 63;
    const int lr   = lane & 15;
    const int kc   = (lane >> 4) * 8;
    const int row0 = blockIdx.x * 64;

    const short* fb = (const short*)fbf;
    const short* wg = (const short*)wT;

    {
        const int sr = tid >> 2, sk = (tid & 3) * 8;
#pragma unroll
        for (int i = 0; i < 3; ++i)
            *(bf16x8*)&As[sr * 104 + sk + 32 * i] =
                *(const bf16x8*)&fb[(size_t)(row0 + sr) * 96 + sk + 32 * i];
        for (int i = tid; i < 1152; i += 256) {
            const int r = i / 12, ko = (i % 12) * 8;
            *(bf16x8*)&Ws[r * 104 + ko] = *(const bf16x8*)&wg[(size_t)r * 96 + ko];
        }
    }
    __syncthreads();

    f32x4 acc[6];
#pragma unroll
    for (int i = 0; i < 6; ++i) acc[i] = f32x4{0.f, 0.f, 0.f, 0.f};

#pragma unroll
    for (int k0 = 0; k0 < 96; k0 += 32) {
        const bf16x8 av = *(const bf16x8*)&As[(wave * 16 + lr) * 104 + k0 + kc];
#pragma unroll
        for (int ct = 0; ct < 6; ++ct) {
            const bf16x8 bv = *(const bf16x8*)&Ws[(ct * 16 + lr) * 104 + k0 + kc];
            acc[ct] = __builtin_amdgcn_mfma_f32_16x16x32_bf16(av, bv, acc[ct], 0, 0, 0);
        }
    }

    const int er = wave * 16 + ((lane >> 4) << 2);
#pragma unroll
    for (int ct = 0; ct < 6; ++ct) {
        const int col = ct * 16 + lr;
#pragma unroll
        for (int r = 0; r < 4; ++r)
            y[(size_t)(row0 + er + r) * 96 + col] = acc[ct][r];
    }
}

// ---------------------------------------------------------------------------
// Head: out = fbf @ w_ppt^T + c_pp  (A resident; 4 n-tiles of 64).
// ---------------------------------------------------------------------------
__global__ __launch_bounds__(256) void head_kernel(
    const __hip_bfloat16* __restrict__ fbf,
    const __hip_bfloat16* __restrict__ wT,     // [256][96]
    const float* __restrict__ c_pp,
    float* __restrict__ out)
{
    __shared__ short As[64 * 104];
    __shared__ short Bs[64 * 104];
    __shared__ float cpps[256];

    const int tid  = threadIdx.x;
    const int wave = tid >> 6;
    const int lane = tid & 63;
    const int lr   = lane & 15;
    const int kc   = (lane >> 4) * 8;
    const int row0 = blockIdx.x * 64;

    const short* fb = (const short*)fbf;
    const short* wg = (const short*)wT;

    {
        const int sr = tid >> 2, sk = (tid & 3) * 8;
#pragma unroll
        for (int i = 0; i < 3; ++i)
            *(bf16x8*)&As[sr * 104 + sk + 32 * i] =
                *(const bf16x8*)&fb[(size_t)(row0 + sr) * 96 + sk + 32 * i];
        if (tid < 256) cpps[tid] = c_pp[tid];
    }

    for (int nt = 0; nt < 4; ++nt) {
        __syncthreads();
        {
            const int sr = tid >> 2, sk = (tid & 3) * 8;
#pragma unroll
            for (int i = 0; i < 3; ++i)
                *(bf16x8*)&Bs[sr * 104 + sk + 32 * i] =
                    *(const bf16x8*)&wg[(size_t)(nt * 64 + sr) * 96 + sk + 32 * i];
        }
        __syncthreads();

        f32x4 acc[4];
#pragma unroll
        for (int i = 0; i < 4; ++i) acc[i] = f32x4{0.f, 0.f, 0.f, 0.f};
#pragma unroll
        for (int k0 = 0; k0 < 96; k0 += 32) {
            const bf16x8 av = *(const bf16x8*)&As[(wave * 16 + lr) * 104 + k0 + kc];
#pragma unroll
            for (int ct = 0; ct < 4; ++ct) {
                const bf16x8 bv = *(const bf16x8*)&Bs[(ct * 16 + lr) * 104 + k0 + kc];
                acc[ct] = __builtin_amdgcn_mfma_f32_16x16x32_bf16(av, bv, acc[ct], 0, 0, 0);
            }
        }

        const int er = wave * 16 + ((lane >> 4) << 2);
#pragma unroll
        for (int ct = 0; ct < 4; ++ct) {
            const int col = nt * 64 + ct * 16 + lr;
#pragma unroll
            for (int r = 0; r < 4; ++r)
                out[(size_t)(row0 + er + r) * 256 + col] = acc[ct][r] + cpps[col];
        }
    }
}

// ---------------------------------------------------------------------------
// LFP gather-max:  f[p] += ( max_k y[knn[p][k]] - y[p] ) * g + b; emits bf16 f.
// ---------------------------------------------------------------------------
__global__ __launch_bounds__(256) void gathermax_kernel(
    const float* __restrict__ y, const int* __restrict__ knn,
    const float* __restrict__ g, const float* __restrict__ b,
    float* __restrict__ f, __hip_bfloat16* __restrict__ fbf)
{
    __shared__ int knns[16][16];
    const int tid = threadIdx.x;
    const int pl  = tid >> 4;
    const int t   = tid & 15;
    const int p0  = blockIdx.x * 16;
    knns[pl][t] = knn[(p0 + pl) * KNB + t];
    __syncthreads();

    const int p   = p0 + pl;
    const int off = t * 6;

    float m[6];
#pragma unroll
    for (int i = 0; i < 6; ++i) m[i] = -INFINITY;

#pragma unroll 4
    for (int k = 0; k < 16; ++k) {
        const int j = knns[pl][k];
        const float* yr = y + (size_t)j * 96 + off;
        const float2 v0 = *(const float2*)(yr + 0);
        const float2 v1 = *(const float2*)(yr + 2);
        const float2 v2 = *(const float2*)(yr + 4);
        m[0] = fmaxf(m[0], v0.x); m[1] = fmaxf(m[1], v0.y);
        m[2] = fmaxf(m[2], v1.x); m[3] = fmaxf(m[3], v1.y);
        m[4] = fmaxf(m[4], v2.x); m[5] = fmaxf(m[5], v2.y);
    }

    const float* yc = y + (size_t)p * 96 + off;
    float* fr = f + (size_t)p * 96 + off;
    __hip_bfloat16* fbr = fbf + (size_t)p * 96 + off;
#pragma unroll
    for (int i = 0; i < 6; ++i) {
        const float nf = fr[i] + (m[i] - yc[i]) * g[off + i] + b[off + i];
        fr[i] = nf;
        fbr[i] = __float2bfloat16(nf);
    }
}

// ---------------------------------------------------------------------------
extern "C" void kernel_launch(void* const* d_in, const int* in_sizes, int n_in,
                              void* d_out, int out_size, void* d_ws, size_t ws_size,
                              hipStream_t stream)
{
    const float* x     = (const float*)d_in[0];
    const float* xyz   = (const float*)d_in[1];
    const int*   knn   = (const int*)d_in[2];
    const float* ne_w1 = (const float*)d_in[3];
    const float* ne_g1 = (const float*)d_in[4];
    const float* ne_b1 = (const float*)d_in[5];
    const float* ne_w2 = (const float*)d_in[6];
    const float* ne_g2 = (const float*)d_in[7];
    const float* ne_b2 = (const float*)d_in[8];
    const float* ne_w3 = (const float*)d_in[9];
    const float* nbr_g = (const float*)d_in[10];
    const float* nbr_b = (const float*)d_in[11];
    const float* m0_w1 = (const float*)d_in[12];
    const float* m0_b1 = (const float*)d_in[13];
    const float* m0_w2 = (const float*)d_in[14];
    const float* m0_g  = (const float*)d_in[15];
    const float* m0_b  = (const float*)d_in[16];
    const float* lfp_w = (const float*)d_in[17];
    const float* lfp_g = (const float*)d_in[18];
    const float* lfp_b = (const float*)d_in[19];
    const float* ms_w1 = (const float*)d_in[20];
    const float* ms_b1 = (const float*)d_in[21];
    const float* ms_w2 = (const float*)d_in[22];
    const float* ms_g  = (const float*)d_in[23];
    const float* ms_b  = (const float*)d_in[24];
    const float* pp_g  = (const float*)d_in[25];
    const float* pp_b  = (const float*)d_in[26];
    const float* pp_w  = (const float*)d_in[27];

    float* out = (float*)d_out;

    // --- workspace layout (all 16B-aligned); h buffer no longer needed ---
    float* f   = (float*)d_ws;                            // [N][96] f32
    float* y   = f + (size_t)NPTS * 96;                   // [N][96] f32
    __hip_bfloat16* fbf = (__hip_bfloat16*)(y + (size_t)NPTS * 96);  // [N][96] bf16
    __hip_bfloat16* w_m0w1t = fbf + (size_t)NPTS * 96;    // [384][96]
    __hip_bfloat16* w_m0w2t = w_m0w1t + 36864;            // [96][384]
    __hip_bfloat16* w_msw1t = w_m0w2t + 36864;            // 2x[384][96]
    __hip_bfloat16* w_msw2t = w_msw1t + 2 * 36864;        // 2x[96][384]
    __hip_bfloat16* w_lfpt  = w_msw2t + 2 * 36864;        // 4x[96][96]
    __hip_bfloat16* w_ppt   = w_lfpt + 4 * 9216;          // [256][96]
    float* c_pp = (float*)(w_ppt + 24576);                // [256] f32

    prep_weights<<<1105, 256, 0, stream>>>(
        m0_w1, m0_w2, ms_w1, ms_w2, lfp_w, pp_w, pp_g, pp_b,
        w_m0w1t, w_m0w2t, w_msw1t, w_msw2t, w_lfpt, w_ppt, c_pp);

    ne_kernel<<<NPTS / 16, 256, 0, stream>>>(x, xyz, knn,
        ne_w1, ne_g1, ne_b1, ne_w2, ne_g2, ne_b2, ne_w3, nbr_g, nbr_b, f, fbf);

    mlp_fused<<<NPTS / 64, 256, 0, stream>>>(
        w_m0w1t, m0_b1, w_m0w2t, m0_g, m0_b, f, fbf);

    for (int i = 0; i < 4; ++i) {
        proj_kernel<<<NPTS / 64, 256, 0, stream>>>(
            fbf, w_lfpt + (size_t)i * 9216, y);
        gathermax_kernel<<<NPTS / 16, 256, 0, stream>>>(
            y, knn, lfp_g + i * 96, lfp_b + i * 96, f, fbf);
        if (i & 1) {
            const int jj = i / 2;
            mlp_fused<<<NPTS / 64, 256, 0, stream>>>(
                w_msw1t + (size_t)jj * 36864, ms_b1 + (size_t)jj * 384,
                w_msw2t + (size_t)jj * 36864, ms_g + jj * 96, ms_b + jj * 96, f, fbf);
        }
    }

    head_kernel<<<NPTS / 64, 256, 0, stream>>>(fbf, w_ppt, c_pp, out);
}